// Round 2
// baseline (280.130 us; speedup 1.0000x reference)
//
#include <hip/hip_runtime.h>
#include <cfloat>

// Shapes: z_e [32,64,64,64] fp32, codebook [512,64] fp32.
// d_out (fp32, flat): z_q_st [8388608] ++ indices [131072] ++ loss [1].
constexpr int C_DIM    = 64;
constexpr int K_CODES  = 512;
constexpr int HW       = 4096;            // 64*64
constexpr int CHW      = C_DIM * HW;      // 262144
constexpr int NPTS     = 131072;          // 32*4096
constexpr int ZQ_SIZE  = 8388608;
constexpr int IDX_OFF  = ZQ_SIZE;
constexpr int LOSS_OFF = ZQ_SIZE + NPTS;

__global__ void vq_zero_loss(float* __restrict__ out) {
    out[LOSS_OFF] = 0.0f;
}

// numpy pairwise_sum over 64 contiguous fp32 squares, 8-accumulator scheme:
//   r[j] = p[j]; r[j] += p[8+j]; ... ; r[j] += p[56+j]
//   res  = ((r0+r1)+(r2+r3)) + ((r4+r5)+(r6+r7))
// Products rounded fp32 BEFORE the adds (numpy materializes z*z first).
// All ops via _rn intrinsics to forbid contraction/reassociation.
template <int STRIDE>
__device__ __forceinline__ float np_sumsq64(const float* __restrict__ a) {
    float r[8];
#pragma unroll
    for (int j = 0; j < 8; ++j) {
        const float v = a[j * STRIDE];
        r[j] = __fmul_rn(v, v);
    }
#pragma unroll
    for (int i = 8; i < 64; i += 8) {
#pragma unroll
        for (int j = 0; j < 8; ++j) {
            const float v = a[(i + j) * STRIDE];
            r[j] = __fadd_rn(r[j], __fmul_rn(v, v));
        }
    }
    return __fadd_rn(
        __fadd_rn(__fadd_rn(r[0], r[1]), __fadd_rn(r[2], r[3])),
        __fadd_rn(__fadd_rn(r[4], r[5]), __fadd_rn(r[6], r[7])));
}

__global__ __launch_bounds__(256) void vq_main(const float* __restrict__ ze,
                                               const float* __restrict__ cb,
                                               float* __restrict__ out)
{
    __shared__ float  Bk[K_CODES];
    __shared__ double lredd[4];

    const int tid = threadIdx.x;

    // B_k = np.sum(cb*cb, axis=1), numpy pairwise order.
    for (int k = tid; k < K_CODES; k += 256) {
        Bk[k] = np_sumsq64<1>(cb + k * C_DIM);
    }
    __syncthreads();

    const int n  = blockIdx.x * 256 + tid;   // grid == NPTS/256 blocks
    const int b  = n >> 12;
    const int hw = n & (HW - 1);

    // Load the point's 64 channels (coalesced across lanes).
    const float* zp = ze + b * CHW + hw;
    float x[C_DIM];
#pragma unroll
    for (int c = 0; c < C_DIM; ++c) x[c] = zp[c * HW];

    // A_n = np.sum(x*x), numpy pairwise order (stride-1 in register array).
    float A;
    {
        float r[8];
#pragma unroll
        for (int j = 0; j < 8; ++j) r[j] = __fmul_rn(x[j], x[j]);
#pragma unroll
        for (int i = 8; i < 64; i += 8) {
#pragma unroll
            for (int j = 0; j < 8; ++j)
                r[j] = __fadd_rn(r[j], __fmul_rn(x[i + j], x[i + j]));
        }
        A = __fadd_rn(
            __fadd_rn(__fadd_rn(r[0], r[1]), __fadd_rn(r[2], r[3])),
            __fadd_rn(__fadd_rn(r[4], r[5]), __fadd_rn(r[6], r[7])));
    }

    // Scan all codes. M_nk replicates sgemm: one sequential fp32 FMA chain
    // over c=0..63, ascending, acc starts at 0 (products unrounded = FMA).
    // dists = fl(fl(A+B_k) - 2*M): 2*M exact, so fmaf(-2, M, T1) == ref.
    float dmin = FLT_MAX;
    int   imin = 0;

    for (int k = 0; k < K_CODES; k += 4) {
        const float4* e4 = (const float4*)(cb + k * C_DIM);  // wave-uniform
        float acc0 = 0.f, acc1 = 0.f, acc2 = 0.f, acc3 = 0.f;
#pragma unroll
        for (int c4 = 0; c4 < 16; ++c4) {
            const float x0 = x[4 * c4 + 0];
            const float x1 = x[4 * c4 + 1];
            const float x2 = x[4 * c4 + 2];
            const float x3 = x[4 * c4 + 3];
            float4 v0 = e4[c4];
            float4 v1 = e4[16 + c4];
            float4 v2 = e4[32 + c4];
            float4 v3 = e4[48 + c4];
            acc0 = fmaf(x0, v0.x, acc0); acc0 = fmaf(x1, v0.y, acc0);
            acc0 = fmaf(x2, v0.z, acc0); acc0 = fmaf(x3, v0.w, acc0);
            acc1 = fmaf(x0, v1.x, acc1); acc1 = fmaf(x1, v1.y, acc1);
            acc1 = fmaf(x2, v1.z, acc1); acc1 = fmaf(x3, v1.w, acc1);
            acc2 = fmaf(x0, v2.x, acc2); acc2 = fmaf(x1, v2.y, acc2);
            acc2 = fmaf(x2, v2.z, acc2); acc2 = fmaf(x3, v2.w, acc2);
            acc3 = fmaf(x0, v3.x, acc3); acc3 = fmaf(x1, v3.y, acc3);
            acc3 = fmaf(x2, v3.z, acc3); acc3 = fmaf(x3, v3.w, acc3);
        }
        {
            const float D = fmaf(-2.0f, acc0, __fadd_rn(A, Bk[k + 0]));
            if (D < dmin) { dmin = D; imin = k + 0; }
        }
        {
            const float D = fmaf(-2.0f, acc1, __fadd_rn(A, Bk[k + 1]));
            if (D < dmin) { dmin = D; imin = k + 1; }
        }
        {
            const float D = fmaf(-2.0f, acc2, __fadd_rn(A, Bk[k + 2]));
            if (D < dmin) { dmin = D; imin = k + 2; }
        }
        {
            const float D = fmaf(-2.0f, acc3, __fadd_rn(A, Bk[k + 3]));
            if (D < dmin) { dmin = D; imin = k + 3; }
        }
    }

    // Outputs.
    out[IDX_OFF + n] = (float)imin;

    const float4* ebest = (const float4*)(cb + imin * C_DIM);
    float* op = out + b * CHW + hw;
    double lsum = 0.0;
#pragma unroll
    for (int c4 = 0; c4 < 16; ++c4) {
        float4 q = ebest[c4];
        float qv[4] = {q.x, q.y, q.z, q.w};
#pragma unroll
        for (int j = 0; j < 4; ++j) {
            const float xe = x[4 * c4 + j];
            const float d  = __fsub_rn(qv[j], xe);      // ref: z_q - z_e
            op[(4 * c4 + j) * HW] = __fadd_rn(xe, d);   // ref: z_e + (...)
            lsum = fma((double)d, (double)d, lsum);
        }
    }

    // loss = 1.25 * mean(d^2); accumulate in fp64, one atomic per block.
#pragma unroll
    for (int off = 32; off > 0; off >>= 1)
        lsum += __shfl_xor(lsum, off, 64);
    if ((tid & 63) == 0) lredd[tid >> 6] = lsum;
    __syncthreads();
    if (tid == 0) {
        const double t = lredd[0] + lredd[1] + lredd[2] + lredd[3];
        atomicAdd(out + LOSS_OFF, (float)(t * (1.25 / (double)ZQ_SIZE)));
    }
}

extern "C" void kernel_launch(void* const* d_in, const int* in_sizes, int n_in,
                              void* d_out, int out_size, void* d_ws, size_t ws_size,
                              hipStream_t stream) {
    (void)in_sizes; (void)n_in; (void)d_ws; (void)ws_size; (void)out_size;
    const float* ze = (const float*)d_in[0];
    const float* cb = (const float*)d_in[1];
    float* out = (float*)d_out;

    vq_zero_loss<<<1, 1, 0, stream>>>(out);
    vq_main<<<NPTS / 256, 256, 0, stream>>>(ze, cb, out);
}

// Round 3
// 279.835 us; speedup vs baseline: 1.0011x; 1.0011x over previous
//
#include <hip/hip_runtime.h>
#include <cfloat>

// Shapes: z_e [32,64,64,64] fp32, codebook [512,64] fp32.
// d_out (fp32, flat): z_q_st [8388608] ++ indices [131072] ++ loss [1].
constexpr int C_DIM    = 64;
constexpr int K_CODES  = 512;
constexpr int HW       = 4096;            // 64*64
constexpr int CHW      = C_DIM * HW;      // 262144
constexpr int NPTS     = 131072;          // 32*4096
constexpr int ZQ_SIZE  = 8388608;
constexpr int IDX_OFF  = ZQ_SIZE;
constexpr int LOSS_OFF = ZQ_SIZE + NPTS;

__global__ void vq_zero_loss(float* __restrict__ out) {
    out[LOSS_OFF] = 0.0f;
}

// numpy pairwise_sum over 64 fp32 squares, 8-accumulator scheme (bit-exact
// vs np.sum of a materialized product array).
template <int STRIDE>
__device__ __forceinline__ float np_sumsq64(const float* __restrict__ a) {
    float r[8];
#pragma unroll
    for (int j = 0; j < 8; ++j) {
        const float v = a[j * STRIDE];
        r[j] = __fmul_rn(v, v);
    }
#pragma unroll
    for (int i = 8; i < 64; i += 8) {
#pragma unroll
        for (int j = 0; j < 8; ++j) {
            const float v = a[(i + j) * STRIDE];
            r[j] = __fadd_rn(r[j], __fmul_rn(v, v));
        }
    }
    return __fadd_rn(
        __fadd_rn(__fadd_rn(r[0], r[1]), __fadd_rn(r[2], r[3])),
        __fadd_rn(__fadd_rn(r[4], r[5]), __fadd_rn(r[6], r[7])));
}

__global__ __launch_bounds__(256, 2) void vq_main(const float* __restrict__ ze,
                                                  const float* __restrict__ cb,
                                                  float* __restrict__ out)
{
    __shared__ float  Bk[K_CODES];
    __shared__ double lredd[4];

    const int tid = threadIdx.x;

    // B_k = np.sum(cb*cb, axis=1), numpy pairwise order.
    for (int k = tid; k < K_CODES; k += 256) {
        Bk[k] = np_sumsq64<1>(cb + k * C_DIM);
    }
    __syncthreads();

    const int n  = blockIdx.x * 256 + tid;   // grid == NPTS/256 blocks
    const int b  = n >> 12;
    const int hw = n & (HW - 1);

    // Load the point's 64 channels (coalesced across lanes), then PIN them
    // in VGPRs: the empty asm makes each value opaque so the compiler cannot
    // sink/rematerialize the global loads into the k-loop (that re-loading
    // was round-2's bottleneck: VGPR_Count=52, ~4 TB of L1/L2 re-reads).
    const float* zp = ze + b * CHW + hw;
    float x[C_DIM];
#pragma unroll
    for (int c = 0; c < C_DIM; ++c) x[c] = zp[c * HW];
#pragma unroll
    for (int c = 0; c < C_DIM; ++c) asm volatile("" : "+v"(x[c]));

    // A_n = np.sum(x*x), numpy pairwise order.
    float A;
    {
        float r[8];
#pragma unroll
        for (int j = 0; j < 8; ++j) r[j] = __fmul_rn(x[j], x[j]);
#pragma unroll
        for (int i = 8; i < 64; i += 8) {
#pragma unroll
            for (int j = 0; j < 8; ++j)
                r[j] = __fadd_rn(r[j], __fmul_rn(x[i + j], x[i + j]));
        }
        A = __fadd_rn(
            __fadd_rn(__fadd_rn(r[0], r[1]), __fadd_rn(r[2], r[3])),
            __fadd_rn(__fadd_rn(r[4], r[5]), __fadd_rn(r[6], r[7])));
    }

    // Scan all codes. M_nk replicates sgemm: one sequential fp32 FMA chain
    // over c=0..63 ascending, acc starts at 0. dists = fl(fl(A+B_k) - 2*M);
    // 2*M is exact so fmaf(-2, M, T1) reproduces the single rounding.
    // Codebook addresses are wave-uniform -> SMEM (s_load) + v_fma with
    // SGPR operand: no VMEM in the hot loop.
    float dmin = FLT_MAX;
    int   imin = 0;

    for (int k = 0; k < K_CODES; k += 4) {
        const float4* e4 = (const float4*)(cb + k * C_DIM);  // wave-uniform
        float acc0 = 0.f, acc1 = 0.f, acc2 = 0.f, acc3 = 0.f;
#pragma unroll
        for (int c4 = 0; c4 < 16; ++c4) {
            const float x0 = x[4 * c4 + 0];
            const float x1 = x[4 * c4 + 1];
            const float x2 = x[4 * c4 + 2];
            const float x3 = x[4 * c4 + 3];
            float4 v0 = e4[c4];
            float4 v1 = e4[16 + c4];
            float4 v2 = e4[32 + c4];
            float4 v3 = e4[48 + c4];
            acc0 = fmaf(x0, v0.x, acc0); acc0 = fmaf(x1, v0.y, acc0);
            acc0 = fmaf(x2, v0.z, acc0); acc0 = fmaf(x3, v0.w, acc0);
            acc1 = fmaf(x0, v1.x, acc1); acc1 = fmaf(x1, v1.y, acc1);
            acc1 = fmaf(x2, v1.z, acc1); acc1 = fmaf(x3, v1.w, acc1);
            acc2 = fmaf(x0, v2.x, acc2); acc2 = fmaf(x1, v2.y, acc2);
            acc2 = fmaf(x2, v2.z, acc2); acc2 = fmaf(x3, v2.w, acc2);
            acc3 = fmaf(x0, v3.x, acc3); acc3 = fmaf(x1, v3.y, acc3);
            acc3 = fmaf(x2, v3.z, acc3); acc3 = fmaf(x3, v3.w, acc3);
        }
        {
            const float D = fmaf(-2.0f, acc0, __fadd_rn(A, Bk[k + 0]));
            if (D < dmin) { dmin = D; imin = k + 0; }
        }
        {
            const float D = fmaf(-2.0f, acc1, __fadd_rn(A, Bk[k + 1]));
            if (D < dmin) { dmin = D; imin = k + 1; }
        }
        {
            const float D = fmaf(-2.0f, acc2, __fadd_rn(A, Bk[k + 2]));
            if (D < dmin) { dmin = D; imin = k + 2; }
        }
        {
            const float D = fmaf(-2.0f, acc3, __fadd_rn(A, Bk[k + 3]));
            if (D < dmin) { dmin = D; imin = k + 3; }
        }
    }

    // Outputs.
    out[IDX_OFF + n] = (float)imin;

    const float4* ebest = (const float4*)(cb + imin * C_DIM);
    float* op = out + b * CHW + hw;
    double lsum = 0.0;
#pragma unroll
    for (int c4 = 0; c4 < 16; ++c4) {
        float4 q = ebest[c4];
        float qv[4] = {q.x, q.y, q.z, q.w};
#pragma unroll
        for (int j = 0; j < 4; ++j) {
            const float xe = x[4 * c4 + j];
            const float d  = __fsub_rn(qv[j], xe);      // ref: z_q - z_e
            op[(4 * c4 + j) * HW] = __fadd_rn(xe, d);   // ref: z_e + (...)
            lsum = fma((double)d, (double)d, lsum);
        }
    }

    // loss = 1.25 * mean(d^2); fp64 accumulate, one atomic per block.
#pragma unroll
    for (int off = 32; off > 0; off >>= 1)
        lsum += __shfl_xor(lsum, off, 64);
    if ((tid & 63) == 0) lredd[tid >> 6] = lsum;
    __syncthreads();
    if (tid == 0) {
        const double t = lredd[0] + lredd[1] + lredd[2] + lredd[3];
        atomicAdd(out + LOSS_OFF, (float)(t * (1.25 / (double)ZQ_SIZE)));
    }
}

extern "C" void kernel_launch(void* const* d_in, const int* in_sizes, int n_in,
                              void* d_out, int out_size, void* d_ws, size_t ws_size,
                              hipStream_t stream) {
    (void)in_sizes; (void)n_in; (void)d_ws; (void)ws_size; (void)out_size;
    const float* ze = (const float*)d_in[0];
    const float* cb = (const float*)d_in[1];
    float* out = (float*)d_out;

    vq_zero_loss<<<1, 1, 0, stream>>>(out);
    vq_main<<<NPTS / 256, 256, 0, stream>>>(ze, cb, out);
}